// Round 2
// baseline (3438.013 us; speedup 1.0000x reference)
//
#include <hip/hip_runtime.h>
#include <hip/hip_fp16.h>

#define TPB 1024

typedef _Float16 h2v __attribute__((ext_vector_type(2)));

__device__ __forceinline__ float dot2f(unsigned int a, unsigned int b, float c) {
#if __has_builtin(__builtin_amdgcn_fdot2)
    return __builtin_amdgcn_fdot2(__builtin_bit_cast(h2v, a), __builtin_bit_cast(h2v, b), c, false);
#else
    float2 af = __half22float2(__builtin_bit_cast(__half2, a));
    float2 bf = __half22float2(__builtin_bit_cast(__half2, b));
    return fmaf(af.y, bf.y, fmaf(af.x, bf.x, c));
#endif
}

__device__ __forceinline__ unsigned int pack2(float a, float b) {
    unsigned int lo = (unsigned int)__half_as_ushort(__float2half_rn(a));
    unsigned int hi = (unsigned int)__half_as_ushort(__float2half_rn(b));
    return lo | (hi << 16);
}

__device__ __forceinline__ float softplus_f(float x) {
    return fmaxf(x, 0.f) + __logf(1.f + __expf(-fabsf(x)));
}
__device__ __forceinline__ float tanh_f(float x) {
    float e = __expf(2.f * x);
    return 1.f - 2.f / (e + 1.f);
}
__device__ __forceinline__ float sigmoid_f(float x) {
    return 1.f / (1.f + __expf(-x));
}

__global__ __launch_bounds__(TPB, 4) void ncde_kernel(
    const float* __restrict__ timestamps, const float* __restrict__ obs,
    const float* __restrict__ coef_d, const float* __restrict__ coef_c,
    const float* __restrict__ coef_b, const float* __restrict__ coef_a,
    const float* __restrict__ gru_wih, const float* __restrict__ gru_whh,
    const float* __restrict__ gru_bih, const float* __restrict__ gru_bhh,
    const float* __restrict__ gru_lin_w,
    const float* __restrict__ ie_w0, const float* __restrict__ ie_b0,
    const float* __restrict__ ie_wh, const float* __restrict__ ie_bh,
    const float* __restrict__ ie_wout, const float* __restrict__ ie_bout,
    const float* __restrict__ vf_w0, const float* __restrict__ vf_b0,
    const float* __restrict__ vf_wh, const float* __restrict__ vf_bh,
    const float* __restrict__ vf_wout, const float* __restrict__ vf_bout,
    const float* __restrict__ dec_w0, const float* __restrict__ dec_b0,
    const float* __restrict__ dec_wh, const float* __restrict__ dec_bh,
    const float* __restrict__ dec_wout, const float* __restrict__ dec_bout,
    float* __restrict__ out)
{
    const int b = blockIdx.x;
    const int tid = threadIdx.x;

    __shared__ __align__(16) float s_ysall[128][64];   // all y states (for decoder)
    __shared__ __align__(16) float s_whh[192 * 65];    // GRU Whh, padded rows
    __shared__ __align__(16) float s_wih[192 * 9];     // GRU Wih, padded
    __shared__ __align__(16) float s_obs[24 * 8];
    __shared__ float s_gi[192];
    __shared__ float s_gh[192];
    __shared__ __align__(16) float s_y[64];            // ODE state (also GRU hidden early)
    __shared__ __align__(16) float s_ysg[64];          // stage input y
    __shared__ __align__(16) __half s_h1h[128];
    __shared__ __align__(16) __half s_h2h[128];
    __shared__ float s_k[6][64];
    __shared__ float s_bi[16], s_ci[16], s_di[16];
    __shared__ __align__(16) float s_v48[48];
    __shared__ float s_m1[128], s_m2[128];
    __shared__ float s_A[6][5];
    __shared__ float s_C[6];
    __shared__ float s_Bw[6];

    // ---- RK (Dopri5) tables ----
    if (tid == 0) {
        const float A[6][5] = {
            {0.f, 0.f, 0.f, 0.f, 0.f},
            {0.2f, 0.f, 0.f, 0.f, 0.f},
            {3.f / 40.f, 9.f / 40.f, 0.f, 0.f, 0.f},
            {44.f / 45.f, -56.f / 15.f, 32.f / 9.f, 0.f, 0.f},
            {19372.f / 6561.f, -25360.f / 2187.f, 64448.f / 6561.f, -212.f / 729.f, 0.f},
            {9017.f / 3168.f, -355.f / 33.f, 46732.f / 5247.f, 49.f / 176.f, -5103.f / 18656.f}};
        const float C[6] = {0.f, 0.2f, 0.3f, 0.8f, 8.f / 9.f, 1.f};
        const float Bw[6] = {35.f / 384.f, 0.f, 500.f / 1113.f, 125.f / 192.f,
                             -2187.f / 6784.f, 11.f / 84.f};
        for (int i = 0; i < 6; ++i) {
            s_C[i] = C[i];
            s_Bw[i] = Bw[i];
            for (int m = 0; m < 5; ++m) s_A[i][m] = A[i][m];
        }
    }

    // ---- stage GRU weights into LDS ----
    for (int idx = tid; idx < 192 * 64; idx += TPB)
        s_whh[(idx >> 6) * 65 + (idx & 63)] = gru_whh[idx];
    for (int idx = tid; idx < 192 * 8; idx += TPB)
        s_wih[(idx >> 3) * 9 + (idx & 7)] = gru_wih[idx];
    if (tid < 24 * 8) s_obs[tid] = obs[(size_t)b * 192 + tid];
    const float bih_r = (tid < 192) ? gru_bih[tid] : 0.f;
    const float bhh_r = (tid < 192) ? gru_bhh[tid] : 0.f;
    if (tid < 64) s_y[tid] = 0.f;   // GRU hidden init
    __syncthreads();

    // ---- GRU over 24 steps ----
    for (int step = 0; step < 24; ++step) {
        if (tid < 192) {
            float gi = bih_r;
            const float* wr = &s_wih[tid * 9];
            const float* xr = &s_obs[step * 8];
#pragma unroll
            for (int j = 0; j < 8; ++j) gi = fmaf(wr[j], xr[j], gi);
            float g0 = bhh_r, g1 = 0.f, g2 = 0.f, g3 = 0.f;
            const float* hr = &s_whh[tid * 65];
#pragma unroll 4
            for (int j = 0; j < 64; j += 4) {
                g0 = fmaf(hr[j + 0], s_y[j + 0], g0);
                g1 = fmaf(hr[j + 1], s_y[j + 1], g1);
                g2 = fmaf(hr[j + 2], s_y[j + 2], g2);
                g3 = fmaf(hr[j + 3], s_y[j + 3], g3);
            }
            s_gi[tid] = gi;
            s_gh[tid] = (g0 + g1) + (g2 + g3);
        }
        __syncthreads();
        if (tid < 64) {
            float rg = sigmoid_f(s_gi[tid] + s_gh[tid]);
            float zg = sigmoid_f(s_gi[64 + tid] + s_gh[64 + tid]);
            float ng = tanh_f(s_gi[128 + tid] + rg * s_gh[128 + tid]);
            s_y[tid] = (1.f - zg) * ng + zg * s_y[tid];
        }
        __syncthreads();
    }

    // ---- enc = gru_lin_w @ hT ; concat with x0 = coef_a[b,0,:] ----
    if (tid < 32) {
        float e = 0.f;
        const float* wr = gru_lin_w + tid * 64;
        for (int j = 0; j < 64; ++j) e = fmaf(wr[j], s_y[j], e);
        s_v48[tid] = e;
    } else if (tid < 48) {
        s_v48[tid] = coef_a[(size_t)b * 127 * 16 + (tid - 32)];
    }
    __syncthreads();

    // ---- initial-embedding MLP: 48 -> 128 -> 128 -> 64 ----
    if (tid < 128) {
        float a = ie_b0[tid];
        const float* wr = ie_w0 + tid * 48;
        for (int j = 0; j < 48; ++j) a = fmaf(wr[j], s_v48[j], a);
        s_m1[tid] = fmaxf(a, 0.f);
    }
    __syncthreads();
    if (tid < 128) {
        float a = ie_bh[tid];
        const float* wr = ie_wh + tid * 128;
        for (int j = 0; j < 128; ++j) a = fmaf(wr[j], s_m1[j], a);
        s_m2[tid] = fmaxf(a, 0.f);
    }
    __syncthreads();
    if (tid < 64) {
        float a = ie_bout[tid];
        const float* wr = ie_wout + tid * 128;
        for (int j = 0; j < 128; ++j) a = fmaf(wr[j], s_m2[j], a);
        s_y[tid] = a;
        s_ysg[tid] = a;
        s_ysall[0][tid] = a;
    }
    __syncthreads();

    // ---- vector-field weights into registers (no spill: ~110 VGPRs) ----
    const int row8 = tid >> 3, seg8 = tid & 7;   // 8 threads per 128-row
    float w0_r[8];          // vf_w0[row8, seg8*8 .. +8]  (fp32)
    {
        const float* base = vf_w0 + row8 * 64 + seg8 * 8;
#pragma unroll
        for (int j = 0; j < 8; ++j) w0_r[j] = base[j];
    }
    unsigned int wh_r[8];   // vf_wh[row8, seg8*16 .. +16] (fp16 pairs)
    {
        const float* base = vf_wh + row8 * 128 + seg8 * 16;
#pragma unroll
        for (int j = 0; j < 8; ++j) wh_r[j] = pack2(base[2 * j], base[2 * j + 1]);
    }
    unsigned int wq[64];    // vf_wout row tid (fp16 pairs)
    {
        const float* r0 = vf_wout + (size_t)tid * 128;
#pragma unroll
        for (int j = 0; j < 64; ++j) wq[j] = pack2(r0[2 * j], r0[2 * j + 1]);
    }
    const float b0_r = vf_b0[row8];
    const float bh_r = vf_bh[row8];
    const float bo = vf_bout[tid];
    const int l_idx = tid >> 4;       // output row l of V(64,16)
    const int c_idx = tid & 15;       // dx column

    const size_t cofs = (size_t)b * 127 * 16;

    // ---- main ODE loop: 127 intervals x 2 substeps x 6 stages ----
#pragma unroll 1
    for (int t = 0; t < 127; ++t) {
        if (tid < 16) s_bi[tid] = coef_b[cofs + t * 16 + tid];
        else if (tid < 32) s_ci[tid - 16] = coef_c[cofs + t * 16 + (tid - 16)];
        else if (tid < 48) s_di[tid - 32] = coef_d[cofs + t * 16 + (tid - 32)];
        const float t0 = timestamps[t], t1 = timestamps[t + 1];
        const float hstep = (t1 - t0) * 0.5f;
        __syncthreads();

#pragma unroll 1
        for (int sub = 0; sub < 2; ++sub) {
            const float f0 = (float)sub * hstep;
#pragma unroll 1
            for (int s = 0; s < 6; ++s) {
                // stage input y_s (s==0: s_ysg already holds y)
                if (s > 0) {
                    if (tid < 64) {
                        float yv = s_y[tid];
                        for (int m = 0; m < s; ++m)
                            yv = fmaf(hstep * s_A[s][m], s_k[m][tid], yv);
                        s_ysg[tid] = yv;
                    }
                    __syncthreads();
                }

                // W0: h1 = softplus(vf_w0 @ y_s + b0)  (8 threads/row, fp32)
                {
                    const float* yb = &s_ysg[seg8 * 8];
                    float4 y0 = *reinterpret_cast<const float4*>(yb);
                    float4 y1 = *reinterpret_cast<const float4*>(yb + 4);
                    float a0 = w0_r[0] * y0.x, a1 = w0_r[1] * y0.y;
                    a0 = fmaf(w0_r[2], y0.z, a0);
                    a1 = fmaf(w0_r[3], y0.w, a1);
                    a0 = fmaf(w0_r[4], y1.x, a0);
                    a1 = fmaf(w0_r[5], y1.y, a1);
                    a0 = fmaf(w0_r[6], y1.z, a0);
                    a1 = fmaf(w0_r[7], y1.w, a1);
                    float a = a0 + a1;
                    a += __shfl_xor(a, 1);
                    a += __shfl_xor(a, 2);
                    a += __shfl_xor(a, 4);
                    if (seg8 == 0) s_h1h[row8] = __float2half_rn(softplus_f(a + b0_r));
                }
                __syncthreads();

                // Wh: h2 = softplus(vf_wh @ h1 + bh)  (8 threads/row, fp16 dot2)
                {
                    const __half* hb = &s_h1h[seg8 * 16];
                    uint4 h0 = *reinterpret_cast<const uint4*>(hb);
                    uint4 h1v = *reinterpret_cast<const uint4*>(hb + 8);
                    float a0 = dot2f(wh_r[0], h0.x, 0.f);
                    float a1 = dot2f(wh_r[1], h0.y, 0.f);
                    a0 = dot2f(wh_r[2], h0.z, a0);
                    a1 = dot2f(wh_r[3], h0.w, a1);
                    a0 = dot2f(wh_r[4], h1v.x, a0);
                    a1 = dot2f(wh_r[5], h1v.y, a1);
                    a0 = dot2f(wh_r[6], h1v.z, a0);
                    a1 = dot2f(wh_r[7], h1v.w, a1);
                    float a = a0 + a1;
                    a += __shfl_xor(a, 1);
                    a += __shfl_xor(a, 2);
                    a += __shfl_xor(a, 4);
                    if (seg8 == 0) s_h2h[row8] = __float2half_rn(softplus_f(a + bh_r));
                }
                __syncthreads();

                // Wout + contraction: V=tanh(wout@h2+bout); k_s[l]=sum_c V[l,c]*dx[c]
                {
                    float a0 = 0.f, a1 = 0.f, a2 = 0.f, a3 = 0.f;
#pragma unroll
                    for (int k4 = 0; k4 < 16; ++k4) {
                        uint4 hv = *reinterpret_cast<const uint4*>(&s_h2h[8 * k4]);
                        a0 = dot2f(wq[4 * k4 + 0], hv.x, a0);
                        a1 = dot2f(wq[4 * k4 + 1], hv.y, a1);
                        a2 = dot2f(wq[4 * k4 + 2], hv.z, a2);
                        a3 = dot2f(wq[4 * k4 + 3], hv.w, a3);
                    }
                    float v = tanh_f((a0 + a1) + (a2 + a3) + bo);
                    // dx for this thread's column
                    float frac = fmaf(s_C[s], hstep, f0);
                    float dx = fmaf(3.f * s_di[c_idx], frac * frac,
                                    fmaf(2.f * s_ci[c_idx], frac, s_bi[c_idx]));
                    float p = v * dx;
                    p += __shfl_xor(p, 1);
                    p += __shfl_xor(p, 2);
                    p += __shfl_xor(p, 4);
                    p += __shfl_xor(p, 8);
                    if (c_idx == 0) s_k[s][l_idx] = p;
                }
                __syncthreads();
            } // stages

            // y update (Dopri5 b-weights); also primes s_ysg for next stage-0
            if (tid < 64) {
                float yv = s_y[tid];
#pragma unroll
                for (int m = 0; m < 6; ++m)
                    yv = fmaf(hstep * s_Bw[m], s_k[m][tid], yv);
                s_y[tid] = yv;
                s_ysg[tid] = yv;
                if (sub == 1) s_ysall[t + 1][tid] = yv;
            }
            __syncthreads();
        } // sub
    } // t

    // ---- decoder: per timestep 64 -> 32 -> 32 -> 8 (relu, relu, ident) ----
    const int wid = tid >> 6, lane = tid & 63;
    for (int t = wid; t < 128; t += 16) {
        const float* yy = s_ysall[t];
        float h1d = 0.f;
        if (lane < 32) {
            float a = dec_b0[lane];
            const float* wr = dec_w0 + lane * 64;
            for (int j = 0; j < 64; ++j) a = fmaf(wr[j], yy[j], a);
            h1d = fmaxf(a, 0.f);
        }
        float a2 = (lane < 32) ? dec_bh[lane] : 0.f;
#pragma unroll 8
        for (int j = 0; j < 32; ++j) {
            float hj = __shfl(h1d, j);
            if (lane < 32) a2 = fmaf(dec_wh[lane * 32 + j], hj, a2);
        }
        float h2d = fmaxf(a2, 0.f);
        float o = (lane < 8) ? dec_bout[lane] : 0.f;
#pragma unroll 8
        for (int j = 0; j < 32; ++j) {
            float hj = __shfl(h2d, j);
            if (lane < 8) o = fmaf(dec_wout[lane * 32 + j], hj, o);
        }
        if (lane < 8) out[(size_t)b * 1024 + t * 8 + lane] = o;
    }
}

extern "C" void kernel_launch(void* const* d_in, const int* in_sizes, int n_in,
                              void* d_out, int out_size, void* d_ws, size_t ws_size,
                              hipStream_t stream) {
    const float* p[29];
    for (int i = 0; i < 29; ++i) p[i] = (const float*)d_in[i];
    ncde_kernel<<<256, TPB, 0, stream>>>(
        p[0], p[1], p[2], p[3], p[4], p[5], p[6], p[7], p[8], p[9], p[10],
        p[11], p[12], p[13], p[14], p[15], p[16], p[17], p[18], p[19], p[20],
        p[21], p[22], p[23], p[24], p[25], p[26], p[27], p[28],
        (float*)d_out);
}

// Round 3
// 3403.331 us; speedup vs baseline: 1.0102x; 1.0102x over previous
//
#include <hip/hip_runtime.h>
#include <hip/hip_fp16.h>

#define TPB 1024

typedef _Float16 h2v __attribute__((ext_vector_type(2)));

__device__ __forceinline__ float dot2f(unsigned int a, unsigned int b, float c) {
#if __has_builtin(__builtin_amdgcn_fdot2)
    return __builtin_amdgcn_fdot2(__builtin_bit_cast(h2v, a), __builtin_bit_cast(h2v, b), c, false);
#else
    float2 af = __half22float2(__builtin_bit_cast(__half2, a));
    float2 bf = __half22float2(__builtin_bit_cast(__half2, b));
    return fmaf(af.y, bf.y, fmaf(af.x, bf.x, c));
#endif
}

__device__ __forceinline__ unsigned int pack2(float a, float b) {
    unsigned int lo = (unsigned int)__half_as_ushort(__float2half_rn(a));
    unsigned int hi = (unsigned int)__half_as_ushort(__float2half_rn(b));
    return lo | (hi << 16);
}

__device__ __forceinline__ float softplus_f(float x) {
    return fmaxf(x, 0.f) + __logf(1.f + __expf(-fabsf(x)));
}
__device__ __forceinline__ float tanh_f(float x) {
    float e = __expf(2.f * x);
    return 1.f - 2.f / (e + 1.f);
}
__device__ __forceinline__ float sigmoid_f(float x) {
    return 1.f / (1.f + __expf(-x));
}

__device__ __forceinline__ float dot8(const float* w, const float* base) {
    float4 a = *reinterpret_cast<const float4*>(base);
    float4 b = *reinterpret_cast<const float4*>(base + 4);
    float s0 = w[0] * a.x, s1 = w[1] * a.y;
    s0 = fmaf(w[2], a.z, s0);
    s1 = fmaf(w[3], a.w, s1);
    s0 = fmaf(w[4], b.x, s0);
    s1 = fmaf(w[5], b.y, s1);
    s0 = fmaf(w[6], b.z, s0);
    s1 = fmaf(w[7], b.w, s1);
    return s0 + s1;
}

__global__ __launch_bounds__(TPB, 1) void ncde_kernel(
    const float* __restrict__ timestamps, const float* __restrict__ obs,
    const float* __restrict__ coef_d, const float* __restrict__ coef_c,
    const float* __restrict__ coef_b, const float* __restrict__ coef_a,
    const float* __restrict__ gru_wih, const float* __restrict__ gru_whh,
    const float* __restrict__ gru_bih, const float* __restrict__ gru_bhh,
    const float* __restrict__ gru_lin_w,
    const float* __restrict__ ie_w0, const float* __restrict__ ie_b0,
    const float* __restrict__ ie_wh, const float* __restrict__ ie_bh,
    const float* __restrict__ ie_wout, const float* __restrict__ ie_bout,
    const float* __restrict__ vf_w0, const float* __restrict__ vf_b0,
    const float* __restrict__ vf_wh, const float* __restrict__ vf_bh,
    const float* __restrict__ vf_wout, const float* __restrict__ vf_bout,
    const float* __restrict__ dec_w0, const float* __restrict__ dec_b0,
    const float* __restrict__ dec_wh, const float* __restrict__ dec_bh,
    const float* __restrict__ dec_wout, const float* __restrict__ dec_bout,
    float* __restrict__ out)
{
    const int b = blockIdx.x;
    const int tid = threadIdx.x;

    __shared__ __align__(16) float s_ysall[128][64];   // all y states (for decoder)
    __shared__ __align__(16) float s_whh[192 * 65];    // GRU Whh, padded rows
    __shared__ __align__(16) float s_wih[192 * 9];     // GRU Wih, padded
    __shared__ __align__(16) float s_obs[24 * 8];
    __shared__ float s_gi[192];
    __shared__ float s_gh[192];
    __shared__ __align__(16) float s_y[64];            // ODE state (also GRU hidden early)
    __shared__ __align__(16) __half s_h1h[128];
    __shared__ __align__(16) __half s_h2h[128];
    __shared__ __align__(16) float s_k[6][64];
    __shared__ float s_bi[16], s_ci[16], s_di[16];
    __shared__ __align__(16) float s_v48[48];
    __shared__ float s_m1[128], s_m2[128];

    // ---- stage GRU weights into LDS ----
    for (int idx = tid; idx < 192 * 64; idx += TPB)
        s_whh[(idx >> 6) * 65 + (idx & 63)] = gru_whh[idx];
    for (int idx = tid; idx < 192 * 8; idx += TPB)
        s_wih[(idx >> 3) * 9 + (idx & 7)] = gru_wih[idx];
    if (tid < 24 * 8) s_obs[tid] = obs[(size_t)b * 192 + tid];
    const float bih_r = (tid < 192) ? gru_bih[tid] : 0.f;
    const float bhh_r = (tid < 192) ? gru_bhh[tid] : 0.f;
    if (tid < 64) s_y[tid] = 0.f;   // GRU hidden init
    __syncthreads();

    // ---- GRU over 24 steps ----
    for (int step = 0; step < 24; ++step) {
        if (tid < 192) {
            float gi = bih_r;
            const float* wr = &s_wih[tid * 9];
            const float* xr = &s_obs[step * 8];
#pragma unroll
            for (int j = 0; j < 8; ++j) gi = fmaf(wr[j], xr[j], gi);
            float g0 = bhh_r, g1 = 0.f, g2 = 0.f, g3 = 0.f;
            const float* hr = &s_whh[tid * 65];
#pragma unroll 4
            for (int j = 0; j < 64; j += 4) {
                g0 = fmaf(hr[j + 0], s_y[j + 0], g0);
                g1 = fmaf(hr[j + 1], s_y[j + 1], g1);
                g2 = fmaf(hr[j + 2], s_y[j + 2], g2);
                g3 = fmaf(hr[j + 3], s_y[j + 3], g3);
            }
            s_gi[tid] = gi;
            s_gh[tid] = (g0 + g1) + (g2 + g3);
        }
        __syncthreads();
        if (tid < 64) {
            float rg = sigmoid_f(s_gi[tid] + s_gh[tid]);
            float zg = sigmoid_f(s_gi[64 + tid] + s_gh[64 + tid]);
            float ng = tanh_f(s_gi[128 + tid] + rg * s_gh[128 + tid]);
            s_y[tid] = (1.f - zg) * ng + zg * s_y[tid];
        }
        __syncthreads();
    }

    // ---- enc = gru_lin_w @ hT ; concat with x0 = coef_a[b,0,:] ----
    if (tid < 32) {
        float e = 0.f;
        const float* wr = gru_lin_w + tid * 64;
        for (int j = 0; j < 64; ++j) e = fmaf(wr[j], s_y[j], e);
        s_v48[tid] = e;
    } else if (tid < 48) {
        s_v48[tid] = coef_a[(size_t)b * 127 * 16 + (tid - 32)];
    }
    __syncthreads();

    // ---- initial-embedding MLP: 48 -> 128 -> 128 -> 64 ----
    if (tid < 128) {
        float a = ie_b0[tid];
        const float* wr = ie_w0 + tid * 48;
        for (int j = 0; j < 48; ++j) a = fmaf(wr[j], s_v48[j], a);
        s_m1[tid] = fmaxf(a, 0.f);
    }
    __syncthreads();
    if (tid < 128) {
        float a = ie_bh[tid];
        const float* wr = ie_wh + tid * 128;
        for (int j = 0; j < 128; ++j) a = fmaf(wr[j], s_m1[j], a);
        s_m2[tid] = fmaxf(a, 0.f);
    }
    __syncthreads();
    if (tid < 64) {
        float a = ie_bout[tid];
        const float* wr = ie_wout + tid * 128;
        for (int j = 0; j < 128; ++j) a = fmaf(wr[j], s_m2[j], a);
        s_y[tid] = a;
        s_ysall[0][tid] = a;
    }
    __syncthreads();

    // ---- vector-field weights into registers (~80 regs, fits 128 cap) ----
    const int row8 = tid >> 3, seg8 = tid & 7;   // 8 threads per 128-row
    float w0_r[8];          // vf_w0[row8, seg8*8 .. +8]  (fp32)
    {
        const float* base = vf_w0 + row8 * 64 + seg8 * 8;
#pragma unroll
        for (int j = 0; j < 8; ++j) w0_r[j] = base[j];
    }
    unsigned int wh_r[8];   // vf_wh[row8, seg8*16 .. +16] (fp16 pairs)
    {
        const float* base = vf_wh + row8 * 128 + seg8 * 16;
#pragma unroll
        for (int j = 0; j < 8; ++j) wh_r[j] = pack2(base[2 * j], base[2 * j + 1]);
    }
    unsigned int wq[64];    // vf_wout row tid (fp16 pairs)
    {
        const float* r0 = vf_wout + (size_t)tid * 128;
#pragma unroll
        for (int j = 0; j < 64; ++j) wq[j] = pack2(r0[2 * j], r0[2 * j + 1]);
    }
    const float b0_r = vf_b0[row8];
    const float bh_r = vf_bh[row8];
    const float bo = vf_bout[tid];
    const int l_idx = tid >> 4;       // output row l of V(64,16)
    const int c_idx = tid & 15;       // dx column

    const size_t cofs = (size_t)b * 127 * 16;

// One RK stage: W0-combine (ACC) -> h1 ; Wh -> h2 ; Wout+contract -> k[S]
#define VF_STAGE(S, ACC, CC)                                                   \
    do {                                                                       \
        {                                                                      \
            float acc_ = (ACC);                                                \
            acc_ += __shfl_xor(acc_, 1);                                       \
            acc_ += __shfl_xor(acc_, 2);                                       \
            acc_ += __shfl_xor(acc_, 4);                                       \
            if (seg8 == 0) s_h1h[row8] = __float2half_rn(softplus_f(acc_ + b0_r)); \
        }                                                                      \
        __syncthreads();                                                       \
        {                                                                      \
            const __half* hb = &s_h1h[seg8 * 16];                              \
            uint4 h0 = *reinterpret_cast<const uint4*>(hb);                    \
            uint4 h1v = *reinterpret_cast<const uint4*>(hb + 8);               \
            float a0 = dot2f(wh_r[0], h0.x, 0.f);                              \
            float a1 = dot2f(wh_r[1], h0.y, 0.f);                              \
            a0 = dot2f(wh_r[2], h0.z, a0);                                     \
            a1 = dot2f(wh_r[3], h0.w, a1);                                     \
            a0 = dot2f(wh_r[4], h1v.x, a0);                                    \
            a1 = dot2f(wh_r[5], h1v.y, a1);                                    \
            a0 = dot2f(wh_r[6], h1v.z, a0);                                    \
            a1 = dot2f(wh_r[7], h1v.w, a1);                                    \
            float a = a0 + a1;                                                 \
            a += __shfl_xor(a, 1);                                             \
            a += __shfl_xor(a, 2);                                             \
            a += __shfl_xor(a, 4);                                             \
            if (seg8 == 0) s_h2h[row8] = __float2half_rn(softplus_f(a + bh_r)); \
        }                                                                      \
        __syncthreads();                                                       \
        {                                                                      \
            float a0 = 0.f, a1 = 0.f, a2 = 0.f, a3 = 0.f;                      \
            _Pragma("unroll")                                                  \
            for (int k4 = 0; k4 < 16; ++k4) {                                  \
                uint4 hv = *reinterpret_cast<const uint4*>(&s_h2h[8 * k4]);    \
                a0 = dot2f(wq[4 * k4 + 0], hv.x, a0);                          \
                a1 = dot2f(wq[4 * k4 + 1], hv.y, a1);                          \
                a2 = dot2f(wq[4 * k4 + 2], hv.z, a2);                          \
                a3 = dot2f(wq[4 * k4 + 3], hv.w, a3);                          \
            }                                                                  \
            float v = tanh_f((a0 + a1) + (a2 + a3) + bo);                      \
            float frac = fmaf((CC), hstep, f0);                                \
            float dxv = fmaf(3.f * s_di[c_idx], frac * frac,                   \
                             fmaf(2.f * s_ci[c_idx], frac, s_bi[c_idx]));      \
            float p = v * dxv;                                                 \
            p += __shfl_xor(p, 1);                                             \
            p += __shfl_xor(p, 2);                                             \
            p += __shfl_xor(p, 4);                                             \
            p += __shfl_xor(p, 8);                                             \
            if (c_idx == 0) s_k[(S)][l_idx] = p;                               \
        }                                                                      \
        __syncthreads();                                                       \
    } while (0)

    // ---- main ODE loop: 127 intervals x 2 substeps x 6 stages ----
#pragma unroll 1
    for (int t = 0; t < 127; ++t) {
        // coef loads: no barrier needed — first use (stage-0 Wout) is 2 barriers away
        if (tid < 16) s_bi[tid] = coef_b[cofs + t * 16 + tid];
        else if (tid < 32) s_ci[tid - 16] = coef_c[cofs + t * 16 + (tid - 16)];
        else if (tid < 48) s_di[tid - 32] = coef_d[cofs + t * 16 + (tid - 32)];
        const float t0 = timestamps[t], t1 = timestamps[t + 1];
        const float hstep = (t1 - t0) * 0.5f;

#pragma unroll 1
        for (int sub = 0; sub < 2; ++sub) {
            const float f0 = (float)sub * hstep;

            float ay = dot8(w0_r, &s_y[seg8 * 8]);
            VF_STAGE(0, ay, 0.f);
            float dk0 = dot8(w0_r, &s_k[0][seg8 * 8]);
            VF_STAGE(1, fmaf(hstep * 0.2f, dk0, ay), 0.2f);
            float dk1 = dot8(w0_r, &s_k[1][seg8 * 8]);
            VF_STAGE(2, fmaf(hstep, fmaf(3.f / 40.f, dk0, (9.f / 40.f) * dk1), ay), 0.3f);
            float dk2 = dot8(w0_r, &s_k[2][seg8 * 8]);
            VF_STAGE(3, fmaf(hstep, fmaf(44.f / 45.f, dk0,
                          fmaf(-56.f / 15.f, dk1, (32.f / 9.f) * dk2)), ay), 0.8f);
            float dk3 = dot8(w0_r, &s_k[3][seg8 * 8]);
            VF_STAGE(4, fmaf(hstep, fmaf(19372.f / 6561.f, dk0,
                          fmaf(-25360.f / 2187.f, dk1,
                          fmaf(64448.f / 6561.f, dk2, (-212.f / 729.f) * dk3))), ay),
                     8.f / 9.f);
            float dk4 = dot8(w0_r, &s_k[4][seg8 * 8]);
            VF_STAGE(5, fmaf(hstep, fmaf(9017.f / 3168.f, dk0,
                          fmaf(-355.f / 33.f, dk1,
                          fmaf(46732.f / 5247.f, dk2,
                          fmaf(49.f / 176.f, dk3, (-5103.f / 18656.f) * dk4)))), ay),
                     1.f);

            // y update (Dopri5 b-weights; b[1]=0)
            if (tid < 64) {
                float yv = s_y[tid];
                yv = fmaf(hstep * (35.f / 384.f), s_k[0][tid], yv);
                yv = fmaf(hstep * (500.f / 1113.f), s_k[2][tid], yv);
                yv = fmaf(hstep * (125.f / 192.f), s_k[3][tid], yv);
                yv = fmaf(hstep * (-2187.f / 6784.f), s_k[4][tid], yv);
                yv = fmaf(hstep * (11.f / 84.f), s_k[5][tid], yv);
                s_y[tid] = yv;
                if (sub == 1) s_ysall[t + 1][tid] = yv;
            }
            __syncthreads();
        } // sub
    } // t

    // ---- decoder: per timestep 64 -> 32 -> 32 -> 8 (relu, relu, ident) ----
    const int wid = tid >> 6, lane = tid & 63;
    for (int t = wid; t < 128; t += 16) {
        const float* yy = s_ysall[t];
        float h1d = 0.f;
        if (lane < 32) {
            float a = dec_b0[lane];
            const float* wr = dec_w0 + lane * 64;
            for (int j = 0; j < 64; ++j) a = fmaf(wr[j], yy[j], a);
            h1d = fmaxf(a, 0.f);
        }
        float a2 = (lane < 32) ? dec_bh[lane] : 0.f;
#pragma unroll 8
        for (int j = 0; j < 32; ++j) {
            float hj = __shfl(h1d, j);
            if (lane < 32) a2 = fmaf(dec_wh[lane * 32 + j], hj, a2);
        }
        float h2d = fmaxf(a2, 0.f);
        float o = (lane < 8) ? dec_bout[lane] : 0.f;
#pragma unroll 8
        for (int j = 0; j < 32; ++j) {
            float hj = __shfl(h2d, j);
            if (lane < 8) o = fmaf(dec_wout[lane * 32 + j], hj, o);
        }
        if (lane < 8) out[(size_t)b * 1024 + t * 8 + lane] = o;
    }
}

extern "C" void kernel_launch(void* const* d_in, const int* in_sizes, int n_in,
                              void* d_out, int out_size, void* d_ws, size_t ws_size,
                              hipStream_t stream) {
    const float* p[29];
    for (int i = 0; i < 29; ++i) p[i] = (const float*)d_in[i];
    ncde_kernel<<<256, TPB, 0, stream>>>(
        p[0], p[1], p[2], p[3], p[4], p[5], p[6], p[7], p[8], p[9], p[10],
        p[11], p[12], p[13], p[14], p[15], p[16], p[17], p[18], p[19], p[20],
        p[21], p[22], p[23], p[24], p[25], p[26], p[27], p[28],
        (float*)d_out);
}

// Round 5
// 2293.291 us; speedup vs baseline: 1.4992x; 1.4840x over previous
//
#include <hip/hip_runtime.h>
#include <hip/hip_fp16.h>

#define TPB 512

typedef _Float16 h2v __attribute__((ext_vector_type(2)));

__device__ __forceinline__ float dot2f(unsigned int a, unsigned int b, float c) {
#if __has_builtin(__builtin_amdgcn_fdot2)
    return __builtin_amdgcn_fdot2(__builtin_bit_cast(h2v, a), __builtin_bit_cast(h2v, b), c, false);
#else
    float2 af = __half22float2(__builtin_bit_cast(__half2, a));
    float2 bf = __half22float2(__builtin_bit_cast(__half2, b));
    return fmaf(af.y, bf.y, fmaf(af.x, bf.x, c));
#endif
}

__device__ __forceinline__ unsigned int pack2(float a, float b) {
    unsigned int lo = (unsigned int)__half_as_ushort(__float2half_rn(a));
    unsigned int hi = (unsigned int)__half_as_ushort(__float2half_rn(b));
    return lo | (hi << 16);
}

__device__ __forceinline__ float softplus_f(float x) {
    return fmaxf(x, 0.f) + __logf(1.f + __expf(-fabsf(x)));
}
__device__ __forceinline__ float tanh_f(float x) {
    float e = __expf(2.f * x);
    return 1.f - 2.f / (e + 1.f);
}
__device__ __forceinline__ float sigmoid_f(float x) {
    return 1.f / (1.f + __expf(-x));
}

// DPP-based partial-wave add-reduce (no LDS, no lgkmcnt):
// 0xB1 = quad_perm(1,0,3,2) (xor1, self-inverse)
// 0x4E = quad_perm(2,3,0,1) (xor2, self-inverse)
// 0x141 = row_half_mirror (lane i <-> (i&~7)|(7-(i&7)); involution, swaps
//         partner quads within each 8-lane group -- direction-safe, unlike row_ror)
template <int CTRL>
__device__ __forceinline__ float dpp_add(float x) {
    int m = __builtin_amdgcn_update_dpp(0, __builtin_bit_cast(int, x), CTRL, 0xF, 0xF, true);
    return x + __builtin_bit_cast(float, m);
}

__device__ __forceinline__ float dot16(const float* w, const float* base) {
    float4 a = *reinterpret_cast<const float4*>(base);
    float4 b = *reinterpret_cast<const float4*>(base + 4);
    float4 c = *reinterpret_cast<const float4*>(base + 8);
    float4 d = *reinterpret_cast<const float4*>(base + 12);
    float s0 = w[0] * a.x, s1 = w[1] * a.y, s2 = w[2] * a.z, s3 = w[3] * a.w;
    s0 = fmaf(w[4], b.x, s0);
    s1 = fmaf(w[5], b.y, s1);
    s2 = fmaf(w[6], b.z, s2);
    s3 = fmaf(w[7], b.w, s3);
    s0 = fmaf(w[8], c.x, s0);
    s1 = fmaf(w[9], c.y, s1);
    s2 = fmaf(w[10], c.z, s2);
    s3 = fmaf(w[11], c.w, s3);
    s0 = fmaf(w[12], d.x, s0);
    s1 = fmaf(w[13], d.y, s1);
    s2 = fmaf(w[14], d.z, s2);
    s3 = fmaf(w[15], d.w, s3);
    return (s0 + s1) + (s2 + s3);
}

__global__ __launch_bounds__(TPB, 1) void ncde_kernel(
    const float* __restrict__ timestamps, const float* __restrict__ obs,
    const float* __restrict__ coef_d, const float* __restrict__ coef_c,
    const float* __restrict__ coef_b, const float* __restrict__ coef_a,
    const float* __restrict__ gru_wih, const float* __restrict__ gru_whh,
    const float* __restrict__ gru_bih, const float* __restrict__ gru_bhh,
    const float* __restrict__ gru_lin_w,
    const float* __restrict__ ie_w0, const float* __restrict__ ie_b0,
    const float* __restrict__ ie_wh, const float* __restrict__ ie_bh,
    const float* __restrict__ ie_wout, const float* __restrict__ ie_bout,
    const float* __restrict__ vf_w0, const float* __restrict__ vf_b0,
    const float* __restrict__ vf_wh, const float* __restrict__ vf_bh,
    const float* __restrict__ vf_wout, const float* __restrict__ vf_bout,
    const float* __restrict__ dec_w0, const float* __restrict__ dec_b0,
    const float* __restrict__ dec_wh, const float* __restrict__ dec_bh,
    const float* __restrict__ dec_wout, const float* __restrict__ dec_bout,
    float* __restrict__ out)
{
    const int b = blockIdx.x;
    const int tid = threadIdx.x;

    __shared__ __align__(16) float s_ysall[128][64];   // all y states (for decoder)
    __shared__ __align__(16) float s_whh[192 * 65];    // GRU Whh, padded rows
    __shared__ __align__(16) float s_wih[192 * 9];     // GRU Wih, padded
    __shared__ __align__(16) float s_obs[24 * 8];
    __shared__ float s_gi[192];
    __shared__ float s_gh[192];
    __shared__ __align__(16) float s_y[64];            // ODE state (also GRU hidden early)
    __shared__ __align__(16) __half s_h1h[128];
    __shared__ __align__(16) __half s_h2h[128];
    __shared__ __align__(16) float s_k[6][64];
    __shared__ float s_bi[16], s_ci[16], s_di[16];
    __shared__ __align__(16) float s_v48[48];
    __shared__ float s_m1[128], s_m2[128];

    // ---- stage GRU weights into LDS ----
    for (int idx = tid; idx < 192 * 64; idx += TPB)
        s_whh[(idx >> 6) * 65 + (idx & 63)] = gru_whh[idx];
    for (int idx = tid; idx < 192 * 8; idx += TPB)
        s_wih[(idx >> 3) * 9 + (idx & 7)] = gru_wih[idx];
    if (tid < 24 * 8) s_obs[tid] = obs[(size_t)b * 192 + tid];
    const float bih_r = (tid < 192) ? gru_bih[tid] : 0.f;
    const float bhh_r = (tid < 192) ? gru_bhh[tid] : 0.f;
    if (tid < 64) s_y[tid] = 0.f;   // GRU hidden init
    __syncthreads();

    // ---- GRU over 24 steps ----
    for (int step = 0; step < 24; ++step) {
        if (tid < 192) {
            float gi = bih_r;
            const float* wr = &s_wih[tid * 9];
            const float* xr = &s_obs[step * 8];
#pragma unroll
            for (int j = 0; j < 8; ++j) gi = fmaf(wr[j], xr[j], gi);
            float g0 = bhh_r, g1 = 0.f, g2 = 0.f, g3 = 0.f;
            const float* hr = &s_whh[tid * 65];
#pragma unroll 4
            for (int j = 0; j < 64; j += 4) {
                g0 = fmaf(hr[j + 0], s_y[j + 0], g0);
                g1 = fmaf(hr[j + 1], s_y[j + 1], g1);
                g2 = fmaf(hr[j + 2], s_y[j + 2], g2);
                g3 = fmaf(hr[j + 3], s_y[j + 3], g3);
            }
            s_gi[tid] = gi;
            s_gh[tid] = (g0 + g1) + (g2 + g3);
        }
        __syncthreads();
        if (tid < 64) {
            float rg = sigmoid_f(s_gi[tid] + s_gh[tid]);
            float zg = sigmoid_f(s_gi[64 + tid] + s_gh[64 + tid]);
            float ng = tanh_f(s_gi[128 + tid] + rg * s_gh[128 + tid]);
            s_y[tid] = (1.f - zg) * ng + zg * s_y[tid];
        }
        __syncthreads();
    }

    // ---- enc = gru_lin_w @ hT ; concat with x0 = coef_a[b,0,:] ----
    if (tid < 32) {
        float e = 0.f;
        const float* wr = gru_lin_w + tid * 64;
        for (int j = 0; j < 64; ++j) e = fmaf(wr[j], s_y[j], e);
        s_v48[tid] = e;
    } else if (tid < 48) {
        s_v48[tid] = coef_a[(size_t)b * 127 * 16 + (tid - 32)];
    }
    __syncthreads();

    // ---- initial-embedding MLP: 48 -> 128 -> 128 -> 64 ----
    if (tid < 128) {
        float a = ie_b0[tid];
        const float* wr = ie_w0 + tid * 48;
        for (int j = 0; j < 48; ++j) a = fmaf(wr[j], s_v48[j], a);
        s_m1[tid] = fmaxf(a, 0.f);
    }
    __syncthreads();
    if (tid < 128) {
        float a = ie_bh[tid];
        const float* wr = ie_wh + tid * 128;
        for (int j = 0; j < 128; ++j) a = fmaf(wr[j], s_m1[j], a);
        s_m2[tid] = fmaxf(a, 0.f);
    }
    __syncthreads();
    if (tid < 64) {
        float a = ie_bout[tid];
        const float* wr = ie_wout + tid * 128;
        for (int j = 0; j < 128; ++j) a = fmaf(wr[j], s_m2[j], a);
        s_y[tid] = a;
        s_ysall[0][tid] = a;
    }
    __syncthreads();

    // ---- vector-field weights into registers (~170 regs; cap 256 at 8 waves) ----
    const int row4 = tid >> 2, seg4 = tid & 3;   // 4 threads per 128-row
    float w0_r[16];          // vf_w0[row4, seg4*16 .. +16]  (fp32)
    {
        const float* base = vf_w0 + row4 * 64 + seg4 * 16;
#pragma unroll
        for (int j = 0; j < 16; ++j) w0_r[j] = base[j];
    }
    unsigned int wh_r[16];   // vf_wh[row4, seg4*32 .. +32] (fp16 pairs)
    {
        const float* base = vf_wh + row4 * 128 + seg4 * 32;
#pragma unroll
        for (int j = 0; j < 16; ++j) wh_r[j] = pack2(base[2 * j], base[2 * j + 1]);
    }
    unsigned int wq0[64], wq1[64];   // vf_wout rows 2*tid, 2*tid+1 (fp16 pairs)
    {
        const float* r0 = vf_wout + (size_t)(2 * tid) * 128;
#pragma unroll
        for (int j = 0; j < 64; ++j) wq0[j] = pack2(r0[2 * j], r0[2 * j + 1]);
        const float* r1 = r0 + 128;
#pragma unroll
        for (int j = 0; j < 64; ++j) wq1[j] = pack2(r1[2 * j], r1[2 * j + 1]);
    }
    const float b0_r = vf_b0[row4];
    const float bh_r = vf_bh[row4];
    const float bo0 = vf_bout[2 * tid], bo1 = vf_bout[2 * tid + 1];
    const int l_idx = tid >> 3;       // output row l of V(64,16)
    const int c0 = 2 * (tid & 7);     // dx columns c0, c0+1

    const size_t cofs = (size_t)b * 127 * 16;

// One RK stage: W0-combine (ACC) -> h1 ; Wh -> h2 ; Wout+contract -> k[S]
#define VF_STAGE(S, ACC, CC)                                                   \
    do {                                                                       \
        {                                                                      \
            float acc_ = (ACC);                                                \
            acc_ = dpp_add<0xB1>(acc_);                                        \
            acc_ = dpp_add<0x4E>(acc_);                                        \
            if (seg4 == 0) s_h1h[row4] = __float2half_rn(softplus_f(acc_ + b0_r)); \
        }                                                                      \
        __syncthreads();                                                       \
        {                                                                      \
            const __half* hb = &s_h1h[seg4 * 32];                              \
            uint4 h0 = *reinterpret_cast<const uint4*>(hb);                    \
            uint4 h1v = *reinterpret_cast<const uint4*>(hb + 8);               \
            uint4 h2v2 = *reinterpret_cast<const uint4*>(hb + 16);             \
            uint4 h3 = *reinterpret_cast<const uint4*>(hb + 24);               \
            float a0 = dot2f(wh_r[0], h0.x, 0.f);                              \
            float a1 = dot2f(wh_r[1], h0.y, 0.f);                              \
            float a2 = dot2f(wh_r[2], h0.z, 0.f);                              \
            float a3 = dot2f(wh_r[3], h0.w, 0.f);                              \
            a0 = dot2f(wh_r[4], h1v.x, a0);                                    \
            a1 = dot2f(wh_r[5], h1v.y, a1);                                    \
            a2 = dot2f(wh_r[6], h1v.z, a2);                                    \
            a3 = dot2f(wh_r[7], h1v.w, a3);                                    \
            a0 = dot2f(wh_r[8], h2v2.x, a0);                                   \
            a1 = dot2f(wh_r[9], h2v2.y, a1);                                   \
            a2 = dot2f(wh_r[10], h2v2.z, a2);                                  \
            a3 = dot2f(wh_r[11], h2v2.w, a3);                                  \
            a0 = dot2f(wh_r[12], h3.x, a0);                                    \
            a1 = dot2f(wh_r[13], h3.y, a1);                                    \
            a2 = dot2f(wh_r[14], h3.z, a2);                                    \
            a3 = dot2f(wh_r[15], h3.w, a3);                                    \
            float a = (a0 + a1) + (a2 + a3);                                   \
            a = dpp_add<0xB1>(a);                                              \
            a = dpp_add<0x4E>(a);                                              \
            if (seg4 == 0) s_h2h[row4] = __float2half_rn(softplus_f(a + bh_r)); \
        }                                                                      \
        __syncthreads();                                                       \
        {                                                                      \
            float a0 = 0.f, a1 = 0.f, b0a = 0.f, b1a = 0.f;                    \
            _Pragma("unroll")                                                  \
            for (int k4 = 0; k4 < 16; ++k4) {                                  \
                uint4 hv = *reinterpret_cast<const uint4*>(&s_h2h[8 * k4]);    \
                a0 = dot2f(wq0[4 * k4 + 0], hv.x, a0);                         \
                b0a = dot2f(wq1[4 * k4 + 0], hv.x, b0a);                       \
                a1 = dot2f(wq0[4 * k4 + 1], hv.y, a1);                         \
                b1a = dot2f(wq1[4 * k4 + 1], hv.y, b1a);                       \
                a0 = dot2f(wq0[4 * k4 + 2], hv.z, a0);                         \
                b0a = dot2f(wq1[4 * k4 + 2], hv.z, b0a);                       \
                a1 = dot2f(wq0[4 * k4 + 3], hv.w, a1);                         \
                b1a = dot2f(wq1[4 * k4 + 3], hv.w, b1a);                       \
            }                                                                  \
            float v0 = tanh_f(a0 + a1 + bo0);                                  \
            float v1 = tanh_f(b0a + b1a + bo1);                                \
            float frac = fmaf((CC), hstep, f0);                                \
            float dx0 = fmaf(3.f * s_di[c0], frac * frac,                      \
                             fmaf(2.f * s_ci[c0], frac, s_bi[c0]));            \
            float dx1 = fmaf(3.f * s_di[c0 + 1], frac * frac,                  \
                             fmaf(2.f * s_ci[c0 + 1], frac, s_bi[c0 + 1]));    \
            float p = fmaf(v0, dx0, v1 * dx1);                                 \
            p = dpp_add<0xB1>(p);                                              \
            p = dpp_add<0x4E>(p);                                              \
            p = dpp_add<0x141>(p);  /* row_half_mirror: direction-safe 8-lane finish */ \
            if ((tid & 7) == 0) s_k[(S)][l_idx] = p;                           \
        }                                                                      \
        __syncthreads();                                                       \
    } while (0)

    // ---- main ODE loop: 127 intervals x 2 substeps x 6 stages ----
#pragma unroll 1
    for (int t = 0; t < 127; ++t) {
        // coef loads: first use (stage-0 Wout) is 2+ barriers away
        if (tid < 16) s_bi[tid] = coef_b[cofs + t * 16 + tid];
        else if (tid < 32) s_ci[tid - 16] = coef_c[cofs + t * 16 + (tid - 16)];
        else if (tid < 48) s_di[tid - 32] = coef_d[cofs + t * 16 + (tid - 32)];
        const float t0 = timestamps[t], t1 = timestamps[t + 1];
        const float hstep = (t1 - t0) * 0.5f;

#pragma unroll 1
        for (int sub = 0; sub < 2; ++sub) {
            const float f0 = (float)sub * hstep;

            float ay = dot16(w0_r, &s_y[seg4 * 16]);
            VF_STAGE(0, ay, 0.f);
            float dk0 = dot16(w0_r, &s_k[0][seg4 * 16]);
            VF_STAGE(1, fmaf(hstep * 0.2f, dk0, ay), 0.2f);
            float dk1 = dot16(w0_r, &s_k[1][seg4 * 16]);
            VF_STAGE(2, fmaf(hstep, fmaf(3.f / 40.f, dk0, (9.f / 40.f) * dk1), ay), 0.3f);
            float dk2 = dot16(w0_r, &s_k[2][seg4 * 16]);
            VF_STAGE(3, fmaf(hstep, fmaf(44.f / 45.f, dk0,
                          fmaf(-56.f / 15.f, dk1, (32.f / 9.f) * dk2)), ay), 0.8f);
            float dk3 = dot16(w0_r, &s_k[3][seg4 * 16]);
            VF_STAGE(4, fmaf(hstep, fmaf(19372.f / 6561.f, dk0,
                          fmaf(-25360.f / 2187.f, dk1,
                          fmaf(64448.f / 6561.f, dk2, (-212.f / 729.f) * dk3))), ay),
                     8.f / 9.f);
            float dk4 = dot16(w0_r, &s_k[4][seg4 * 16]);
            VF_STAGE(5, fmaf(hstep, fmaf(9017.f / 3168.f, dk0,
                          fmaf(-355.f / 33.f, dk1,
                          fmaf(46732.f / 5247.f, dk2,
                          fmaf(49.f / 176.f, dk3, (-5103.f / 18656.f) * dk4)))), ay),
                     1.f);

            // y update (Dopri5 b-weights; b[1]=0)
            if (tid < 64) {
                float yv = s_y[tid];
                yv = fmaf(hstep * (35.f / 384.f), s_k[0][tid], yv);
                yv = fmaf(hstep * (500.f / 1113.f), s_k[2][tid], yv);
                yv = fmaf(hstep * (125.f / 192.f), s_k[3][tid], yv);
                yv = fmaf(hstep * (-2187.f / 6784.f), s_k[4][tid], yv);
                yv = fmaf(hstep * (11.f / 84.f), s_k[5][tid], yv);
                s_y[tid] = yv;
                if (sub == 1) s_ysall[t + 1][tid] = yv;
            }
            __syncthreads();
        } // sub
    } // t

    // ---- decoder: per timestep 64 -> 32 -> 32 -> 8 (relu, relu, ident) ----
    const int wid = tid >> 6, lane = tid & 63;
    for (int t = wid; t < 128; t += 8) {
        const float* yy = s_ysall[t];
        float h1d = 0.f;
        if (lane < 32) {
            float a = dec_b0[lane];
            const float* wr = dec_w0 + lane * 64;
            for (int j = 0; j < 64; ++j) a = fmaf(wr[j], yy[j], a);
            h1d = fmaxf(a, 0.f);
        }
        float a2 = (lane < 32) ? dec_bh[lane] : 0.f;
#pragma unroll 8
        for (int j = 0; j < 32; ++j) {
            float hj = __shfl(h1d, j);
            if (lane < 32) a2 = fmaf(dec_wh[lane * 32 + j], hj, a2);
        }
        float h2d = fmaxf(a2, 0.f);
        float o = (lane < 8) ? dec_bout[lane] : 0.f;
#pragma unroll 8
        for (int j = 0; j < 32; ++j) {
            float hj = __shfl(h2d, j);
            if (lane < 8) o = fmaf(dec_wout[lane * 32 + j], hj, o);
        }
        if (lane < 8) out[(size_t)b * 1024 + t * 8 + lane] = o;
    }
}

extern "C" void kernel_launch(void* const* d_in, const int* in_sizes, int n_in,
                              void* d_out, int out_size, void* d_ws, size_t ws_size,
                              hipStream_t stream) {
    const float* p[29];
    for (int i = 0; i < 29; ++i) p[i] = (const float*)d_in[i];
    ncde_kernel<<<256, TPB, 0, stream>>>(
        p[0], p[1], p[2], p[3], p[4], p[5], p[6], p[7], p[8], p[9], p[10],
        p[11], p[12], p[13], p[14], p[15], p[16], p[17], p[18], p[19], p[20],
        p[21], p[22], p[23], p[24], p[25], p[26], p[27], p[28],
        (float*)d_out);
}